// Round 1
// baseline (17550.410 us; speedup 1.0000x reference)
//
#include <hip/hip_runtime.h>

// Problem constants
#define B_  64
#define T_  2048
#define I_  128
#define H_  256
#define G4  1024   // 4*H
#define TC  128    // timestep chunk

typedef float     f32x4  __attribute__((ext_vector_type(4)));
typedef _Float16  f16x8  __attribute__((ext_vector_type(8)));
typedef _Float16  f16x2  __attribute__((ext_vector_type(2)));

__device__ __forceinline__ float dot2f(unsigned w, unsigned h, float acc) {
#if __has_builtin(__builtin_amdgcn_fdot2)
  return __builtin_amdgcn_fdot2(__builtin_bit_cast(f16x2, w),
                                __builtin_bit_cast(f16x2, h), acc, false);
#else
  f16x2 a = __builtin_bit_cast(f16x2, w), b = __builtin_bit_cast(f16x2, h);
  return acc + (float)a[0] * (float)b[0] + (float)a[1] * (float)b[1];
#endif
}

__device__ __forceinline__ unsigned short h16bits(float f) {
  return __builtin_bit_cast(unsigned short, (_Float16)f);
}

// ---------------- prep kernels ----------------

// Pack W_hh [1024][256] f32 -> uint4 per (kb, j): whh4[kb*1024 + j].q holds
// f16x2 (W[j][2kp], W[j][2kp+1]) with kp = kb*4+q.
__global__ void prep_whh(const float* __restrict__ Whh, uint4* __restrict__ whh4) {
  int idx = blockIdx.x * 256 + threadIdx.x;           // 0..32767
  if (idx >= 32 * 1024) return;
  int kb = idx >> 10, j = idx & 1023;
  unsigned q[4];
#pragma unroll
  for (int t = 0; t < 4; t++) {
    int kp = kb * 4 + t, k = kp * 2;
    unsigned lo = h16bits(Whh[j * 256 + k]);
    unsigned hi = h16bits(Whh[j * 256 + k + 1]);
    q[t] = lo | (hi << 16);
  }
  whh4[idx] = make_uint4(q[0], q[1], q[2], q[3]);
}

__global__ void prep_f16(const float* __restrict__ src, _Float16* __restrict__ dst, int n) {
  int i = blockIdx.x * 256 + threadIdx.x;
  if (i < n) dst[i] = (_Float16)src[i];
}

__global__ void prep_bias(const float* __restrict__ bi, const float* __restrict__ bh,
                          float* __restrict__ bias) {
  int i = blockIdx.x * 256 + threadIdx.x;
  if (i < G4) bias[i] = bi[i] + bh[i];
}

// ---------------- projection GEMM (f16 MFMA) ----------------
// xw[r_g][1024] = A[r_g][K] @ W^T + bias, rows r_g = b*TC + tc (chunk-local).
// A source: layer0 -> x fp32 at (b*T + t0 + tc)*K ; layer1 -> ychunk f16 at r_g*K.
template <int K, bool SRC_F32>
__global__ __launch_bounds__(256) void proj_kernel(const void* __restrict__ Asrc,
                                                   const _Float16* __restrict__ Wf,
                                                   const float* __restrict__ bias,
                                                   float* __restrict__ xw, int t0) {
  const int m  = blockIdx.x;        // M-tile (64 rows)
  const int n0 = blockIdx.y * 64;   // N-tile base
  const int tid = threadIdx.x;
  const int lane = tid & 63, wv = tid >> 6;

  __shared__ _Float16 As[64][40];   // padded stride: 80B -> conflict-light
  __shared__ _Float16 Bs[64][40];

  f32x4 acc[4] = {f32x4{0,0,0,0}, f32x4{0,0,0,0}, f32x4{0,0,0,0}, f32x4{0,0,0,0}};

  const int r  = tid >> 2;          // staging row 0..63
  const int kq = (tid & 3) * 8;     // staging k offset
  const int r_g = m * 64 + r;
  const int b  = r_g >> 7;          // TC = 128
  const int tc = r_g & (TC - 1);
  long arow;
  if (SRC_F32) arow = (long)(b * T_ + t0 + tc) * K;
  else         arow = (long)r_g * K;

  for (int k0 = 0; k0 < K; k0 += 32) {
    if (SRC_F32) {
      const float* ap = (const float*)Asrc + arow + k0 + kq;
      float4 a0 = *(const float4*)ap;
      float4 a1 = *(const float4*)(ap + 4);
      _Float16* d = &As[r][kq];
      d[0] = (_Float16)a0.x; d[1] = (_Float16)a0.y; d[2] = (_Float16)a0.z; d[3] = (_Float16)a0.w;
      d[4] = (_Float16)a1.x; d[5] = (_Float16)a1.y; d[6] = (_Float16)a1.z; d[7] = (_Float16)a1.w;
    } else {
      const _Float16* ap = (const _Float16*)Asrc + arow + k0 + kq;
      *(uint4*)&As[r][kq] = *(const uint4*)ap;
    }
    // B: Wf[n][K] row-major, tile rows n0..n0+63
    *(uint4*)&Bs[r][kq] = *(const uint4*)(Wf + (long)(n0 + r) * K + k0 + kq);
    __syncthreads();

    f16x8 av = *(const f16x8*)&As[wv * 16 + (lane & 15)][(lane >> 4) * 8];
#pragma unroll
    for (int q = 0; q < 4; q++) {
      f16x8 bv = *(const f16x8*)&Bs[q * 16 + (lane & 15)][(lane >> 4) * 8];
      acc[q] = __builtin_amdgcn_mfma_f32_16x16x32_f16(av, bv, acc[q], 0, 0, 0);
    }
    __syncthreads();
  }

  // C/D: row = (lane>>4)*4 + i, col = lane&15  (within 16x16)
  const int row_in = wv * 16 + ((lane >> 4) << 2);
  const int col_in = lane & 15;
#pragma unroll
  for (int q = 0; q < 4; q++) {
#pragma unroll
    for (int i = 0; i < 4; i++) {
      int rr = m * 64 + row_in + i;
      int cc = n0 + q * 16 + col_in;
      xw[(long)rr * G4 + cc] = acc[q][i] + bias[cc];
    }
  }
}

// ---------------- recurrent scan ----------------
// One block per batch element; 1024 threads = one gate row each.
__global__ __launch_bounds__(1024) void scan_kernel(
    const float* __restrict__ xw,      // [B*TC][1024] chunk
    const uint4* __restrict__ whh4,    // [32*1024]
    const float* __restrict__ mask,    // [B][256]
    float* __restrict__ hstate, float* __restrict__ cstate,  // [B][256]
    _Float16* __restrict__ ychunk,     // layer0 out chunk [B*TC][256] (or null)
    float* __restrict__ out,           // layer1: d_out base (or null)
    float* __restrict__ hn, float* __restrict__ cn,          // last chunk only
    int t0) {
  const int b = blockIdx.x;
  const int j = threadIdx.x;

  __shared__ __align__(16) unsigned hs2[128];  // h packed f16x2
  __shared__ float gates[1024];
  __shared__ float maskx[256];

  float c_reg = 0.f, h_reg = 0.f;
  if (j < 256) {
    h_reg = hstate[b * 256 + j];
    c_reg = cstate[b * 256 + j];
    ((unsigned short*)hs2)[j] = h16bits(h_reg);
    maskx[j] = mask[b * 256 + j];
  }
  __syncthreads();

  const uint4* wp  = whh4 + j;
  const float* xwp = xw + (long)b * TC * G4 + j;

  for (int tc = 0; tc < TC; tc++) {
    float acc = xwp[(long)tc * G4];
#pragma unroll 4
    for (int kb = 0; kb < 32; kb++) {
      uint4 wv = wp[kb * 1024];
      uint4 hv = ((const uint4*)hs2)[kb];
      acc = dot2f(wv.x, hv.x, acc);
      acc = dot2f(wv.y, hv.y, acc);
      acc = dot2f(wv.z, hv.z, acc);
      acc = dot2f(wv.w, hv.w, acc);
    }
    // apply own nonlinearity before sharing: i,f,o -> sigmoid ; g -> tanh
    float v = ((j >> 8) == 2) ? tanhf(acc) : 1.f / (1.f + __expf(-acc));
    gates[j] = v;
    __syncthreads();

    if (j < 256) {
      float gi = gates[j], gf = gates[j + 256], gg = gates[j + 512], go = gates[j + 768];
      float c = gf * c_reg + gi * gg;
      float h = go * tanhf(c);
      c_reg = c; h_reg = h;
      ((unsigned short*)hs2)[j] = h16bits(h);
      float hm = h * maskx[j];
      if (ychunk) ychunk[(b * TC + tc) * H_ + j] = (_Float16)hm;
      else        out[(long)(b * T_ + t0 + tc) * H_ + j] = hm;
    }
    __syncthreads();
  }

  if (j < 256) {
    hstate[b * 256 + j] = h_reg;
    cstate[b * 256 + j] = c_reg;
    if (hn) { hn[b * 256 + j] = h_reg; cn[b * 256 + j] = c_reg; }
  }
}

// ---------------- host launch ----------------
extern "C" void kernel_launch(void* const* d_in, const int* in_sizes, int n_in,
                              void* d_out, int out_size, void* d_ws, size_t ws_size,
                              hipStream_t stream) {
  const float* x     = (const float*)d_in[0];
  const float* Wih0  = (const float*)d_in[1];
  const float* Whh0  = (const float*)d_in[2];
  const float* bih0  = (const float*)d_in[3];
  const float* bhh0  = (const float*)d_in[4];
  const float* mask0 = (const float*)d_in[5];
  const float* Wih1  = (const float*)d_in[6];
  const float* Whh1  = (const float*)d_in[7];
  const float* bih1  = (const float*)d_in[8];
  const float* bhh1  = (const float*)d_in[9];
  const float* mask1 = (const float*)d_in[10];

  float* out = (float*)d_out;
  float* hn  = out + (long)B_ * T_ * H_;   // [2][64][256]
  float* cn  = hn + 2 * B_ * H_;

  char* w = (char*)d_ws;
  uint4*    whh4_0 = (uint4*)w;      w += 512 << 10;
  uint4*    whh4_1 = (uint4*)w;      w += 512 << 10;
  _Float16* wf0    = (_Float16*)w;   w += 256 << 10;   // [1024][128]
  _Float16* wf1    = (_Float16*)w;   w += 512 << 10;   // [1024][256]
  float*    bias0  = (float*)w;      w += 4 << 10;
  float*    bias1  = (float*)w;      w += 4 << 10;
  float*    h0s    = (float*)w;      w += 64 << 10;
  float*    c0s    = (float*)w;      w += 64 << 10;
  float*    h1s    = (float*)w;      w += 64 << 10;
  float*    c1s    = (float*)w;      w += 64 << 10;
  float*    xwbuf  = (float*)w;      w += (long)B_ * TC * G4 * 4;   // 32 MB
  _Float16* ybuf   = (_Float16*)w;   w += (long)B_ * TC * H_ * 2;   // 4 MB

  // zero h/c states (contiguous 256KB)
  hipMemsetAsync(h0s, 0, 4 * (64 << 10), stream);

  // weight prep
  prep_whh<<<128, 256, 0, stream>>>(Whh0, whh4_0);
  prep_whh<<<128, 256, 0, stream>>>(Whh1, whh4_1);
  prep_f16<<<512, 256, 0, stream>>>(Wih0, wf0, G4 * I_);
  prep_f16<<<1024, 256, 0, stream>>>(Wih1, wf1, G4 * H_);
  prep_bias<<<4, 256, 0, stream>>>(bih0, bhh0, bias0);
  prep_bias<<<4, 256, 0, stream>>>(bih1, bhh1, bias1);

  const int nchunk = T_ / TC;  // 16
  for (int k = 0; k < nchunk; k++) {
    int t0 = k * TC;
    bool last = (k == nchunk - 1);
    proj_kernel<I_, true><<<dim3(B_ * TC / 64, G4 / 64), 256, 0, stream>>>(
        x, wf0, bias0, xwbuf, t0);
    scan_kernel<<<B_, 1024, 0, stream>>>(xwbuf, whh4_0, mask0, h0s, c0s,
                                         ybuf, nullptr,
                                         last ? hn : nullptr, last ? cn : nullptr, t0);
    proj_kernel<H_, false><<<dim3(B_ * TC / 64, G4 / 64), 256, 0, stream>>>(
        ybuf, wf1, bias1, xwbuf, t0);
    scan_kernel<<<B_, 1024, 0, stream>>>(xwbuf, whh4_1, mask1, h1s, c1s,
                                         nullptr, out,
                                         last ? hn + B_ * H_ : nullptr,
                                         last ? cn + B_ * H_ : nullptr, t0);
  }
}

// Round 2
// 13498.160 us; speedup vs baseline: 1.3002x; 1.3002x over previous
//
#include <hip/hip_runtime.h>

#define B_  64
#define T_  2048
#define I_  128
#define H_  256
#define G4  1024   // 4*H
#define TC  128    // timestep chunk

typedef float    f32x4 __attribute__((ext_vector_type(4)));
typedef _Float16 f16x8 __attribute__((ext_vector_type(8)));
typedef _Float16 f16x2 __attribute__((ext_vector_type(2)));

__device__ __forceinline__ float dot2f(unsigned w, unsigned h, float acc) {
#if __has_builtin(__builtin_amdgcn_fdot2)
  return __builtin_amdgcn_fdot2(__builtin_bit_cast(f16x2, w),
                                __builtin_bit_cast(f16x2, h), acc, false);
#else
  f16x2 a = __builtin_bit_cast(f16x2, w), b = __builtin_bit_cast(f16x2, h);
  return acc + (float)a[0] * (float)b[0] + (float)a[1] * (float)b[1];
#endif
}

__device__ __forceinline__ unsigned short h16bits(float f) {
  return __builtin_bit_cast(unsigned short, (_Float16)f);
}
__device__ __forceinline__ float sigm(float x) { return 1.f / (1.f + __expf(-x)); }
__device__ __forceinline__ float tanh_fast(float x) { return 2.f / (1.f + __expf(-2.f * x)) - 1.f; }

// ---------------- prep kernels ----------------

// W_hh [1024][256] f32 -> packed f16x2 dwords, split into:
//   wregg: [24][1024] uint4  (k-dwords 0..95  -> register-resident in scan)
//   wldsg: [8][1024]  uint4  (k-dwords 96..127 -> LDS-resident in scan)
__global__ void prep_w(const float* __restrict__ Whh,
                       uint4* __restrict__ wregg, uint4* __restrict__ wldsg) {
  int idx = blockIdx.x * 256 + threadIdx.x;   // 0..32767
  if (idx >= 32 * 1024) return;
  int c4 = idx >> 10, r = idx & 1023;         // c4: uint4 index 0..31 along k
  unsigned q[4];
#pragma unroll
  for (int m = 0; m < 4; m++) {
    int kd = 4 * c4 + m;                      // dword index 0..127
    unsigned lo = h16bits(Whh[r * 256 + 2 * kd]);
    unsigned hi = h16bits(Whh[r * 256 + 2 * kd + 1]);
    q[m] = lo | (hi << 16);
  }
  uint4 v = make_uint4(q[0], q[1], q[2], q[3]);
  if (c4 < 24) wregg[c4 * 1024 + r] = v;
  else         wldsg[(c4 - 24) * 1024 + r] = v;
}

__global__ void prep_f16(const float* __restrict__ src, _Float16* __restrict__ dst, int n) {
  int i = blockIdx.x * 256 + threadIdx.x;
  if (i < n) dst[i] = (_Float16)src[i];
}

__global__ void prep_bias(const float* __restrict__ bi, const float* __restrict__ bh,
                          float* __restrict__ bias) {
  int i = blockIdx.x * 256 + threadIdx.x;
  if (i < G4) bias[i] = bi[i] + bh[i];
}

// ---------------- projection GEMM (f16 MFMA) ----------------
template <int K, bool SRC_F32>
__global__ __launch_bounds__(256) void proj_kernel(const void* __restrict__ Asrc,
                                                   const _Float16* __restrict__ Wf,
                                                   const float* __restrict__ bias,
                                                   float* __restrict__ xw, int t0) {
  const int m  = blockIdx.x;        // M-tile (64 rows)
  const int n0 = blockIdx.y * 64;   // N-tile base
  const int tid = threadIdx.x;
  const int lane = tid & 63, wv = tid >> 6;

  __shared__ _Float16 As[64][40];
  __shared__ _Float16 Bs[64][40];

  f32x4 acc[4] = {f32x4{0,0,0,0}, f32x4{0,0,0,0}, f32x4{0,0,0,0}, f32x4{0,0,0,0}};

  const int r  = tid >> 2;
  const int kq = (tid & 3) * 8;
  const int r_g = m * 64 + r;
  const int b  = r_g >> 7;          // TC = 128
  const int tc = r_g & (TC - 1);
  long arow;
  if (SRC_F32) arow = (long)(b * T_ + t0 + tc) * K;
  else         arow = (long)r_g * K;

  for (int k0 = 0; k0 < K; k0 += 32) {
    if (SRC_F32) {
      const float* ap = (const float*)Asrc + arow + k0 + kq;
      float4 a0 = *(const float4*)ap;
      float4 a1 = *(const float4*)(ap + 4);
      _Float16* d = &As[r][kq];
      d[0] = (_Float16)a0.x; d[1] = (_Float16)a0.y; d[2] = (_Float16)a0.z; d[3] = (_Float16)a0.w;
      d[4] = (_Float16)a1.x; d[5] = (_Float16)a1.y; d[6] = (_Float16)a1.z; d[7] = (_Float16)a1.w;
    } else {
      const _Float16* ap = (const _Float16*)Asrc + arow + k0 + kq;
      *(uint4*)&As[r][kq] = *(const uint4*)ap;
    }
    *(uint4*)&Bs[r][kq] = *(const uint4*)(Wf + (long)(n0 + r) * K + k0 + kq);
    __syncthreads();

    f16x8 av = *(const f16x8*)&As[wv * 16 + (lane & 15)][(lane >> 4) * 8];
#pragma unroll
    for (int q = 0; q < 4; q++) {
      f16x8 bv = *(const f16x8*)&Bs[q * 16 + (lane & 15)][(lane >> 4) * 8];
      acc[q] = __builtin_amdgcn_mfma_f32_16x16x32_f16(av, bv, acc[q], 0, 0, 0);
    }
    __syncthreads();
  }

  const int row_in = wv * 16 + ((lane >> 4) << 2);
  const int col_in = lane & 15;
#pragma unroll
  for (int q = 0; q < 4; q++) {
#pragma unroll
    for (int i = 0; i < 4; i++) {
      int rr = m * 64 + row_in + i;
      int cc = n0 + q * 16 + col_in;
      xw[(long)rr * G4 + cc] = acc[q][i] + bias[cc];
    }
  }
}

// ---------------- recurrent scan ----------------
// One block (256 threads) per batch element. Thread j owns h-index j and all
// four gate rows {j, j+256, j+512, j+768}: gate combine is thread-local.
// W head (k-dwords 0..95) register-resident; W tail (96..127) LDS-resident.
__global__ __launch_bounds__(256, 1) void scan_kernel(
    const float* __restrict__ xw,      // [B*TC][1024] chunk
    const uint4* __restrict__ wregg,   // [24][1024]
    const uint4* __restrict__ wldsg,   // [8][1024]
    const float* __restrict__ mask,    // [B][256]
    float* __restrict__ hstate, float* __restrict__ cstate,  // [B][256]
    _Float16* __restrict__ ychunk,     // layer0 out chunk (or null)
    float* __restrict__ out,           // layer1: d_out base (or null)
    float* __restrict__ hn, float* __restrict__ cn,          // last chunk only
    int t0) {
  const int b = blockIdx.x;
  const int j = threadIdx.x;

  __shared__ uint4    wt_lds[8 * 1024];   // 128KB W tail, [q4][row]
  __shared__ unsigned hsb[2][128];        // double-buffered h, packed f16x2

  // stage W tail into LDS (coalesced, conflict-free)
#pragma unroll
  for (int i = 0; i < 32; i++)
    wt_lds[i * 256 + j] = wldsg[i * 256 + j];

  // W head into registers: 4 rows x 24 uint4 = 384 VGPRs
  uint4 w0[24], w1[24], w2[24], w3[24];
#pragma unroll
  for (int c = 0; c < 24; c++) {
    w0[c] = wregg[c * 1024 + j];
    w1[c] = wregg[c * 1024 + j + 256];
    w2[c] = wregg[c * 1024 + j + 512];
    w3[c] = wregg[c * 1024 + j + 768];
  }

  float c_reg = cstate[b * 256 + j];
  float h_reg = hstate[b * 256 + j];
  const float mk = mask[b * 256 + j];
  ((unsigned short*)&hsb[0][0])[j] = h16bits(h_reg);
  __syncthreads();

  const float* xwb = xw + (long)b * TC * G4 + j;
  float x0 = xwb[0], x1 = xwb[256], x2 = xwb[512], x3 = xwb[768];
  float hm_prev = 0.f;

  for (int tc = 0; tc < TC; tc++) {
    // prefetch next step's xw early (hidden under the dot chain)
    const long nx = (long)(tc + 1 < TC ? tc + 1 : tc) * G4;
    float n0 = xwb[nx], n1 = xwb[nx + 256], n2 = xwb[nx + 512], n3 = xwb[nx + 768];

    // store PREVIOUS step's output now, so the vmcnt drain at the barrier
    // overlaps with this step's compute
    if (tc > 0) {
      if (ychunk) ychunk[(b * TC + tc - 1) * H_ + j] = (_Float16)hm_prev;
      else        out[(long)(b * T_ + t0 + tc - 1) * H_ + j] = hm_prev;
    }

    const uint4* hp = (const uint4*)hsb[tc & 1];
    float a0 = x0, a1 = x1, a2 = x2, a3 = x3;
#pragma unroll
    for (int c = 0; c < 24; c++) {
      uint4 hv = hp[c];   // broadcast read
      a0 = dot2f(w0[c].x, hv.x, a0); a1 = dot2f(w1[c].x, hv.x, a1);
      a2 = dot2f(w2[c].x, hv.x, a2); a3 = dot2f(w3[c].x, hv.x, a3);
      a0 = dot2f(w0[c].y, hv.y, a0); a1 = dot2f(w1[c].y, hv.y, a1);
      a2 = dot2f(w2[c].y, hv.y, a2); a3 = dot2f(w3[c].y, hv.y, a3);
      a0 = dot2f(w0[c].z, hv.z, a0); a1 = dot2f(w1[c].z, hv.z, a1);
      a2 = dot2f(w2[c].z, hv.z, a2); a3 = dot2f(w3[c].z, hv.z, a3);
      a0 = dot2f(w0[c].w, hv.w, a0); a1 = dot2f(w1[c].w, hv.w, a1);
      a2 = dot2f(w2[c].w, hv.w, a2); a3 = dot2f(w3[c].w, hv.w, a3);
    }
#pragma unroll
    for (int q = 0; q < 8; q++) {
      uint4 hv  = hp[24 + q];           // broadcast read
      uint4 t0v = wt_lds[q * 1024 + j];          // lane-striped, conflict-free
      uint4 t1v = wt_lds[q * 1024 + j + 256];
      uint4 t2v = wt_lds[q * 1024 + j + 512];
      uint4 t3v = wt_lds[q * 1024 + j + 768];
      a0 = dot2f(t0v.x, hv.x, a0); a1 = dot2f(t1v.x, hv.x, a1);
      a2 = dot2f(t2v.x, hv.x, a2); a3 = dot2f(t3v.x, hv.x, a3);
      a0 = dot2f(t0v.y, hv.y, a0); a1 = dot2f(t1v.y, hv.y, a1);
      a2 = dot2f(t2v.y, hv.y, a2); a3 = dot2f(t3v.y, hv.y, a3);
      a0 = dot2f(t0v.z, hv.z, a0); a1 = dot2f(t1v.z, hv.z, a1);
      a2 = dot2f(t2v.z, hv.z, a2); a3 = dot2f(t3v.z, hv.z, a3);
      a0 = dot2f(t0v.w, hv.w, a0); a1 = dot2f(t1v.w, hv.w, a1);
      a2 = dot2f(t2v.w, hv.w, a2); a3 = dot2f(t3v.w, hv.w, a3);
    }

    // gate order: a0=i[j], a1=f[j], a2=g[j], a3=o[j]  (all local to this thread)
    float ci = sigm(a0), cf = sigm(a1), cg = tanh_fast(a2), co = sigm(a3);
    c_reg = cf * c_reg + ci * cg;
    h_reg = co * tanh_fast(c_reg);
    ((unsigned short*)&hsb[(tc + 1) & 1][0])[j] = h16bits(h_reg);
    hm_prev = h_reg * mk;
    x0 = n0; x1 = n1; x2 = n2; x3 = n3;
    __syncthreads();
  }

  // final output element (tc = TC-1)
  if (ychunk) ychunk[(b * TC + TC - 1) * H_ + j] = (_Float16)hm_prev;
  else        out[(long)(b * T_ + t0 + TC - 1) * H_ + j] = hm_prev;

  hstate[b * 256 + j] = h_reg;
  cstate[b * 256 + j] = c_reg;
  if (hn) { hn[b * 256 + j] = h_reg; cn[b * 256 + j] = c_reg; }
}

// ---------------- host launch ----------------
extern "C" void kernel_launch(void* const* d_in, const int* in_sizes, int n_in,
                              void* d_out, int out_size, void* d_ws, size_t ws_size,
                              hipStream_t stream) {
  const float* x     = (const float*)d_in[0];
  const float* Wih0  = (const float*)d_in[1];
  const float* Whh0  = (const float*)d_in[2];
  const float* bih0  = (const float*)d_in[3];
  const float* bhh0  = (const float*)d_in[4];
  const float* mask0 = (const float*)d_in[5];
  const float* Wih1  = (const float*)d_in[6];
  const float* Whh1  = (const float*)d_in[7];
  const float* bih1  = (const float*)d_in[8];
  const float* bhh1  = (const float*)d_in[9];
  const float* mask1 = (const float*)d_in[10];

  float* out = (float*)d_out;
  float* hn  = out + (long)B_ * T_ * H_;   // [2][64][256]
  float* cn  = hn + 2 * B_ * H_;

  char* w = (char*)d_ws;
  uint4*    wregg0 = (uint4*)w;      w += 384 << 10;   // [24][1024] uint4
  uint4*    wldsg0 = (uint4*)w;      w += 128 << 10;   // [8][1024] uint4
  uint4*    wregg1 = (uint4*)w;      w += 384 << 10;
  uint4*    wldsg1 = (uint4*)w;      w += 128 << 10;
  _Float16* wf0    = (_Float16*)w;   w += 256 << 10;   // [1024][128]
  _Float16* wf1    = (_Float16*)w;   w += 512 << 10;   // [1024][256]
  float*    bias0  = (float*)w;      w += 4 << 10;
  float*    bias1  = (float*)w;      w += 4 << 10;
  float*    h0s    = (float*)w;      w += 64 << 10;
  float*    c0s    = (float*)w;      w += 64 << 10;
  float*    h1s    = (float*)w;      w += 64 << 10;
  float*    c1s    = (float*)w;      w += 64 << 10;
  float*    xwbuf  = (float*)w;      w += (long)B_ * TC * G4 * 4;   // 32 MB
  _Float16* ybuf   = (_Float16*)w;   w += (long)B_ * TC * H_ * 2;   // 4 MB

  // zero h/c states (contiguous 256KB)
  hipMemsetAsync(h0s, 0, 4 * (64 << 10), stream);

  // weight prep
  prep_w<<<128, 256, 0, stream>>>(Whh0, wregg0, wldsg0);
  prep_w<<<128, 256, 0, stream>>>(Whh1, wregg1, wldsg1);
  prep_f16<<<512, 256, 0, stream>>>(Wih0, wf0, G4 * I_);
  prep_f16<<<1024, 256, 0, stream>>>(Wih1, wf1, G4 * H_);
  prep_bias<<<4, 256, 0, stream>>>(bih0, bhh0, bias0);
  prep_bias<<<4, 256, 0, stream>>>(bih1, bhh1, bias1);

  const int nchunk = T_ / TC;  // 16
  for (int k = 0; k < nchunk; k++) {
    int t0 = k * TC;
    bool last = (k == nchunk - 1);
    proj_kernel<I_, true><<<dim3(B_ * TC / 64, G4 / 64), 256, 0, stream>>>(
        x, wf0, bias0, xwbuf, t0);
    scan_kernel<<<B_, 256, 0, stream>>>(xwbuf, wregg0, wldsg0, mask0, h0s, c0s,
                                        ybuf, nullptr,
                                        last ? hn : nullptr, last ? cn : nullptr, t0);
    proj_kernel<H_, false><<<dim3(B_ * TC / 64, G4 / 64), 256, 0, stream>>>(
        ybuf, wf1, bias1, xwbuf, t0);
    scan_kernel<<<B_, 256, 0, stream>>>(xwbuf, wregg1, wldsg1, mask1, h1s, c1s,
                                        nullptr, out,
                                        last ? hn + B_ * H_ : nullptr,
                                        last ? cn + B_ * H_ : nullptr, t0);
  }
}